// Round 7
// baseline (146.039 us; speedup 1.0000x reference)
//
#include <hip/hip_runtime.h>

// Problem constants
#define BATCH   8
#define NNODES  16384
#define KNBR    16
#define LATENT  128
#define DOUT    32
#define NROWS   (BATCH * NNODES)          // 131072 rows

typedef __attribute__((ext_vector_type(8))) short short8;   // 8 bf16 (4 VGPRs)
typedef __attribute__((ext_vector_type(4))) float floatx4;  // MFMA acc

__device__ __forceinline__ unsigned short f2bf(float f) {   // fp32 -> bf16 RNE
    unsigned u = __float_as_uint(f);
    u += 0x7fff + ((u >> 16) & 1);
    return (unsigned short)(u >> 16);
}

__device__ __forceinline__ float dot2bf(unsigned a, unsigned b) {
    float alo = __uint_as_float(a << 16);
    float ahi = __uint_as_float(a & 0xffff0000u);
    float blo = __uint_as_float(b << 16);
    float bhi = __uint_as_float(b & 0xffff0000u);
    return alo * blo + ahi * bhi;
}

// Direct global->LDS 16B copy (no VGPR round-trip). Size must be a literal.
__device__ __forceinline__ void gload_lds16(const float* g, void* l) {
    __builtin_amdgcn_global_load_lds(
        (const __attribute__((address_space(1))) void*)g,
        (__attribute__((address_space(3))) void*)l,
        16, 0, 0);
}

#define BPAD 136    // B row stride: 128 + 8 bf16 (272 B)

// ---------------------------------------------------------------------------
// Kernel 1 (v5): bf16 MFMA projection, SINGLE-STAGE 64-row tiles.
// 64 rows x full K=128 fp32 = 32 KB staged in ONE phase (was 2 chunked
// phases with 2 vmcnt(0) barrier-drains per block). 2048 blocks -> smoother
// tail at 3 blocks/CU. A staged via global_load_lds(16B), XOR swizzle on
// BOTH sides (pre-swizzled global source + swizzled ds_read, rule #21):
//   phys(L) = L ^ ((row&7)<<4), involution within each 512 B row.
// Tile->batch remap: block bid handles batch bid%8 so batch b's table lines
// are written on block-residue b (same XCD residue that gathers them).
// Geometry == round-2 phase-A (refcheck-proven, absmax identical).
// ---------------------------------------------------------------------------
__global__ __launch_bounds__(256) void proj_kernel(
    const float* __restrict__ feats,
    const float* __restrict__ kw, const float* __restrict__ kb,
    const float* __restrict__ qw, const float* __restrict__ qb,
    unsigned short* __restrict__ tkb, unsigned short* __restrict__ tqb)
{
    __shared__ __align__(16) unsigned char A_raw[64 * 512]; // 32 KB fp32 tile
    __shared__ unsigned short B_lds[64 * BPAD];             // 17 KB
    __shared__ float bias_lds[64];

    const int tid  = threadIdx.x;
    const int lane = tid & 63;
    const int w    = tid >> 6;                     // wave 0..3
    const int bat  = blockIdx.x & 7;               // batch == block residue
    const int u    = blockIdx.x >> 3;              // tile within batch, 0..255
    const long long blk_row = (long long)bat * NNODES + (long long)u * 64;

    // Issue A staging FIRST (pure VMEM->LDS, no VGPR dependency), so the
    // loads fly while we stage B through the VALU.
#pragma unroll
    for (int i = 0; i < 8; ++i) {
        const int L  = i * 4096 + tid * 16;
        const int r  = L >> 9;                              // row 0..63
        const int c0 = ((L & 511) ^ ((r & 7) << 4)) >> 2;   // fp32 col
        gload_lds16(feats + (blk_row + r) * 128 + c0, A_raw + L);
    }

    // Stage B = [kw ; qw] as bf16: B_lds[col*BPAD + k] = W_cat[col][k]
    {
        const float4* kw4 = (const float4*)kw;     // [32 rows][32 f4]
        const float4* qw4 = (const float4*)qw;
#pragma unroll
        for (int i = 0; i < 8; ++i) {
            const int linear = i * 256 + tid;      // 0..2047
            const int row = linear >> 5;           // 0..63
            const int c4  = linear & 31;
            const float4 v = (row < 32) ? kw4[row * 32 + c4] : qw4[(row - 32) * 32 + c4];
            unsigned lo = f2bf(v.x) | ((unsigned)f2bf(v.y) << 16);
            unsigned hi = f2bf(v.z) | ((unsigned)f2bf(v.w) << 16);
            *(uint2*)&B_lds[row * BPAD + c4 * 4] = make_uint2(lo, hi);
        }
        if (tid < 64) bias_lds[tid] = (tid < 32) ? kb[tid] : qb[tid - 32];
    }

    __syncthreads();   // one drain: A tile + B/bias visible

    const int m = lane & 15;   // MFMA row (A) / col (B,C)
    const int q = lane >> 4;   // quad

    floatx4 acc[4];
#pragma unroll
    for (int ct = 0; ct < 4; ++ct) acc[ct] = (floatx4){0.f, 0.f, 0.f, 0.f};

    const int rloc = w * 16 + m;       // A row 0..63
    const int sw   = (rloc & 7) << 4;
#pragma unroll
    for (int ks = 0; ks < 4; ++ks) {
        const int b0 = rloc * 512 + ks * 128 + q * 32;  // logical byte
        const int p0 = b0 ^ sw;                         // swizzled
        const float4 a0 = *(const float4*)(A_raw + p0);
        const float4 a1 = *(const float4*)(A_raw + (p0 ^ 16));
        union { short8 s; unsigned uu[4]; } af;
        af.uu[0] = f2bf(a0.x) | ((unsigned)f2bf(a0.y) << 16);
        af.uu[1] = f2bf(a0.z) | ((unsigned)f2bf(a0.w) << 16);
        af.uu[2] = f2bf(a1.x) | ((unsigned)f2bf(a1.y) << 16);
        af.uu[3] = f2bf(a1.z) | ((unsigned)f2bf(a1.w) << 16);
        const int kg = ks * 32 + q * 8;
#pragma unroll
        for (int ct = 0; ct < 4; ++ct) {
            const short8 bf = *(const short8*)&B_lds[(ct * 16 + m) * BPAD + kg];
            acc[ct] = __builtin_amdgcn_mfma_f32_16x16x32_bf16(af.s, bf, acc[ct], 0, 0, 0);
        }
    }

    // Epilogue: bias + bf16 store. C/D layout: col = lane&15, row = q*4+reg.
#pragma unroll
    for (int reg = 0; reg < 4; ++reg) {
        const long long row = blk_row + w * 16 + q * 4 + reg;
#pragma unroll
        for (int ct = 0; ct < 4; ++ct) {
            const float val = acc[ct][reg] + bias_lds[ct * 16 + m];
            if (ct < 2) tkb[row * DOUT + ct * 16 + m]       = f2bf(val);
            else        tqb[row * DOUT + (ct - 2) * 16 + m] = f2bf(val);
        }
    }
}

// ---------------------------------------------------------------------------
// Kernel 2: gather + scaled dot, cooperative-4 v3 (grid-stride x4 for MLP) —
// unchanged from round 6 (measured win).
// 2048 blocks (8/CU). Each thread owns 4 outputs at 65536-output stride: all
// 8 idx loads independent & issued up-front, then 32 table loads in flight.
// Table rows read cooperative-4 (4 lanes x 16 B = one fully-consumed 64 B
// line per row). idx stride-1 coalesced, store fully dense. Tables
// L2-resident & XCD-local (proj batch remap). Nontemporal idx/out.
// ---------------------------------------------------------------------------
__global__ __launch_bounds__(256) void gather_dot_kernel(
    const unsigned short* __restrict__ tkb, const unsigned short* __restrict__ tqb,
    const int* __restrict__ idx, float* __restrict__ out)
{
    const long long NK  = (long long)NNODES * KNBR;     // 262144 per batch
    const long long BNK = NK * BATCH;                   // 2097152 total

    const int bat  = blockIdx.x & 7;
    const int blk  = blockIdx.x >> 3;                   // 0..255
    const int tid  = threadIdx.x;
    const int lane = tid & 63;
    const int j    = tid & 3;                           // uint4 column in row

    const uint4* tb_k = (const uint4*)(tkb + (long long)bat * NNODES * DOUT);
    const uint4* tb_q = (const uint4*)(tqb + (long long)bat * NNODES * DOUT);

    const long long base = (long long)bat * NK + (long long)blk * 256 + tid;

    // All idx loads up-front: 8 independent coalesced nontemporal loads.
    int xi[4], yi[4];
#pragma unroll
    for (int c = 0; c < 4; ++c) {
        const long long o = base + (long long)c * 65536;
        xi[c] = __builtin_nontemporal_load(&idx[BNK + o]);        // channel 1
        yi[c] = __builtin_nontemporal_load(&idx[2 * BNK + o]);    // channel 2
    }

#pragma unroll
    for (int c = 0; c < 4; ++c) {
        float r0, r1, r2, r3;
#pragma unroll
        for (int p = 0; p < 4; ++p) {
            const int xp = __shfl(xi[c], (lane & ~3) | p);   // quad-owner bcast
            const int yp = __shfl(yi[c], (lane & ~3) | p);
            const uint4 x = tb_k[(long long)xp * 4 + j];
            const uint4 y = tb_q[(long long)yp * 4 + j];
            float s = dot2bf(x.x, y.x) + dot2bf(x.y, y.y)
                    + dot2bf(x.z, y.z) + dot2bf(x.w, y.w);
            s += __shfl_xor(s, 1);
            s += __shfl_xor(s, 2);   // all 4 lanes hold the full 32-dim sum
            if      (p == 0) r0 = s;
            else if (p == 1) r1 = s;
            else if (p == 2) r2 = s;
            else             r3 = s;
        }
        // lane j stores pass-j's result -> dense contiguous store
        const float v = (j == 0) ? r0 : (j == 1) ? r1 : (j == 2) ? r2 : r3;
        __builtin_nontemporal_store(v * 0.17677669529663687f,
                                    &out[base + (long long)c * 65536]);
    }
}

// ---------------------------------------------------------------------------
extern "C" void kernel_launch(void* const* d_in, const int* in_sizes, int n_in,
                              void* d_out, int out_size, void* d_ws, size_t ws_size,
                              hipStream_t stream)
{
    const float* feats = (const float*)d_in[0];
    const float* kw    = (const float*)d_in[1];
    const float* kb    = (const float*)d_in[2];
    const float* qw    = (const float*)d_in[3];
    const float* qb    = (const float*)d_in[4];
    const int*   idx   = (const int*)d_in[5];
    float*       out   = (float*)d_out;

    // Workspace: two bf16 tables [B*N, 32] = 8 MB each
    unsigned short* tkb = (unsigned short*)d_ws;
    unsigned short* tqb = tkb + (long long)NROWS * DOUT;

    proj_kernel<<<NROWS / 64, 256, 0, stream>>>(feats, kw, kb, qw, qb, tkb, tqb);
    gather_dot_kernel<<<2048, 256, 0, stream>>>(tkb, tqb, idx, out);
}

// Round 8
// 143.053 us; speedup vs baseline: 1.0209x; 1.0209x over previous
//
#include <hip/hip_runtime.h>

// Problem constants
#define BATCH   8
#define NNODES  16384
#define KNBR    16
#define LATENT  128
#define DOUT    32
#define NROWS   (BATCH * NNODES)          // 131072 rows

typedef __attribute__((ext_vector_type(8))) short short8;   // 8 bf16 (4 VGPRs)
typedef __attribute__((ext_vector_type(4))) float floatx4;  // MFMA acc

__device__ __forceinline__ unsigned short f2bf(float f) {   // fp32 -> bf16 RNE
    unsigned u = __float_as_uint(f);
    u += 0x7fff + ((u >> 16) & 1);
    return (unsigned short)(u >> 16);
}

__device__ __forceinline__ float dot2bf(unsigned a, unsigned b) {
    float alo = __uint_as_float(a << 16);
    float ahi = __uint_as_float(a & 0xffff0000u);
    float blo = __uint_as_float(b << 16);
    float bhi = __uint_as_float(b & 0xffff0000u);
    return alo * blo + ahi * bhi;
}

// Direct global->LDS 16B copy (no VGPR round-trip). Size must be a literal.
__device__ __forceinline__ void gload_lds16(const float* g, void* l) {
    __builtin_amdgcn_global_load_lds(
        (const __attribute__((address_space(1))) void*)g,
        (__attribute__((address_space(3))) void*)l,
        16, 0, 0);
}

#define BPAD 136    // B row stride: 128 + 8 bf16 (272 B)

// ---------------------------------------------------------------------------
// Kernel 1 (v6): round-4/6 proj structure (measured best) at 512 threads.
// 128 rows/block, 8 waves (16 rows/wave). Same 2-chunk staging, same
// B-before-A vmcnt queue ordering (round-7 showed A-first serializes B
// staging behind the gload_lds queue), same XOR swizzle on BOTH sides:
//   phys(L) = L ^ ((row&7)<<4).
// 512 threads @ 49.4 KB LDS -> still 3 blocks/CU but 24 waves/CU (was 12):
// doubled latency-hiding across the stage->drain phases.
// Tile->batch remap: block bid handles batch bid%8 so batch b's table lines
// are written on block-residue b (same XCD residue that gathers them).
// ---------------------------------------------------------------------------
__global__ __launch_bounds__(512) void proj_kernel(
    const float* __restrict__ feats,
    const float* __restrict__ kw, const float* __restrict__ kb,
    const float* __restrict__ qw, const float* __restrict__ qb,
    unsigned short* __restrict__ tkb, unsigned short* __restrict__ tqb)
{
    __shared__ __align__(16) unsigned char A_raw[128 * 256]; // 32 KB fp32 chunk
    __shared__ unsigned short B_lds[64 * BPAD];              // 17 KB
    __shared__ float bias_lds[64];

    const int tid  = threadIdx.x;
    const int lane = tid & 63;
    const int w    = tid >> 6;                     // wave 0..7
    const int bat  = blockIdx.x & 7;               // batch == block residue
    const int u    = blockIdx.x >> 3;              // tile within batch, 0..127
    const long long blk_row = (long long)bat * NNODES + (long long)u * 128;

    // Stage B = [kw ; qw] as bf16 FIRST (oldest in the vmcnt queue, so its
    // consumption never waits on the A gload_lds stream).
    {
        const float4* kw4 = (const float4*)kw;     // [32 rows][32 f4]
        const float4* qw4 = (const float4*)qw;
#pragma unroll
        for (int i = 0; i < 4; ++i) {
            const int linear = i * 512 + tid;      // 0..2047
            const int row = linear >> 5;           // 0..63
            const int c4  = linear & 31;
            const float4 v = (row < 32) ? kw4[row * 32 + c4] : qw4[(row - 32) * 32 + c4];
            unsigned lo = f2bf(v.x) | ((unsigned)f2bf(v.y) << 16);
            unsigned hi = f2bf(v.z) | ((unsigned)f2bf(v.w) << 16);
            *(uint2*)&B_lds[row * BPAD + c4 * 4] = make_uint2(lo, hi);
        }
        if (tid < 64) bias_lds[tid] = (tid < 32) ? kb[tid] : qb[tid - 32];
    }

    const int m = lane & 15;   // MFMA row (A) / col (B,C)
    const int q = lane >> 4;   // quad

    floatx4 acc[4];
#pragma unroll
    for (int ct = 0; ct < 4; ++ct) acc[ct] = (floatx4){0.f, 0.f, 0.f, 0.f};

    for (int ch = 0; ch < 2; ++ch) {
        if (ch) __syncthreads();   // prev chunk fully consumed before overwrite

        // Issue A-chunk staging: 128 rows x 64 fp32 = 32 KB, 4 x 16B/thread.
        // Dest L linear (wave-uniform base + lane*16); source address is the
        // element whose swizzled position is L: col = (L&255)^((row&7)<<4).
#pragma unroll
        for (int i = 0; i < 4; ++i) {
            const int L  = i * 8192 + tid * 16;
            const int r  = L >> 8;                              // 0..127
            const int c0 = (((L & 255) ^ ((r & 7) << 4)) >> 2); // fp32 col
            gload_lds16(feats + (blk_row + r) * 128 + ch * 64 + c0, A_raw + L);
        }
        __syncthreads();   // drains vmcnt -> chunk (and on ch0: B/bias) visible

        const int rloc = w * 16 + m;       // A row 0..127
        const int sw   = (rloc & 7) << 4;
#pragma unroll
        for (int ks = 0; ks < 2; ++ks) {
            const int b0 = rloc * 256 + ks * 128 + q * 32;  // logical byte
            const int p0 = b0 ^ sw;                         // swizzled
            const float4 a0 = *(const float4*)(A_raw + p0);
            const float4 a1 = *(const float4*)(A_raw + (p0 ^ 16));
            union { short8 s; unsigned uu[4]; } af;
            af.uu[0] = f2bf(a0.x) | ((unsigned)f2bf(a0.y) << 16);
            af.uu[1] = f2bf(a0.z) | ((unsigned)f2bf(a0.w) << 16);
            af.uu[2] = f2bf(a1.x) | ((unsigned)f2bf(a1.y) << 16);
            af.uu[3] = f2bf(a1.z) | ((unsigned)f2bf(a1.w) << 16);
            const int kg = ch * 64 + ks * 32 + q * 8;       // global k for B
#pragma unroll
            for (int ct = 0; ct < 4; ++ct) {
                const short8 bf = *(const short8*)&B_lds[(ct * 16 + m) * BPAD + kg];
                acc[ct] = __builtin_amdgcn_mfma_f32_16x16x32_bf16(af.s, bf, acc[ct], 0, 0, 0);
            }
        }
    }

    // Epilogue: bias + bf16 store. C/D layout: col = lane&15, row = q*4+reg.
#pragma unroll
    for (int reg = 0; reg < 4; ++reg) {
        const long long row = blk_row + w * 16 + q * 4 + reg;
#pragma unroll
        for (int ct = 0; ct < 4; ++ct) {
            const float val = acc[ct][reg] + bias_lds[ct * 16 + m];
            if (ct < 2) tkb[row * DOUT + ct * 16 + m]       = f2bf(val);
            else        tqb[row * DOUT + (ct - 2) * 16 + m] = f2bf(val);
        }
    }
}

// ---------------------------------------------------------------------------
// Kernel 2: gather + scaled dot, cooperative-4 v3 (grid-stride x4 for MLP) —
// unchanged from round 6 (measured win).
// 2048 blocks (8/CU). Each thread owns 4 outputs at 65536-output stride: all
// 8 idx loads independent & issued up-front, then 32 table loads in flight.
// Table rows read cooperative-4 (4 lanes x 16 B = one fully-consumed 64 B
// line per row). idx stride-1 coalesced, store fully dense. Tables
// L2-resident & XCD-local (proj batch remap). Nontemporal idx/out.
// ---------------------------------------------------------------------------
__global__ __launch_bounds__(256) void gather_dot_kernel(
    const unsigned short* __restrict__ tkb, const unsigned short* __restrict__ tqb,
    const int* __restrict__ idx, float* __restrict__ out)
{
    const long long NK  = (long long)NNODES * KNBR;     // 262144 per batch
    const long long BNK = NK * BATCH;                   // 2097152 total

    const int bat  = blockIdx.x & 7;
    const int blk  = blockIdx.x >> 3;                   // 0..255
    const int tid  = threadIdx.x;
    const int lane = tid & 63;
    const int j    = tid & 3;                           // uint4 column in row

    const uint4* tb_k = (const uint4*)(tkb + (long long)bat * NNODES * DOUT);
    const uint4* tb_q = (const uint4*)(tqb + (long long)bat * NNODES * DOUT);

    const long long base = (long long)bat * NK + (long long)blk * 256 + tid;

    // All idx loads up-front: 8 independent coalesced nontemporal loads.
    int xi[4], yi[4];
#pragma unroll
    for (int c = 0; c < 4; ++c) {
        const long long o = base + (long long)c * 65536;
        xi[c] = __builtin_nontemporal_load(&idx[BNK + o]);        // channel 1
        yi[c] = __builtin_nontemporal_load(&idx[2 * BNK + o]);    // channel 2
    }

#pragma unroll
    for (int c = 0; c < 4; ++c) {
        float r0, r1, r2, r3;
#pragma unroll
        for (int p = 0; p < 4; ++p) {
            const int xp = __shfl(xi[c], (lane & ~3) | p);   // quad-owner bcast
            const int yp = __shfl(yi[c], (lane & ~3) | p);
            const uint4 x = tb_k[(long long)xp * 4 + j];
            const uint4 y = tb_q[(long long)yp * 4 + j];
            float s = dot2bf(x.x, y.x) + dot2bf(x.y, y.y)
                    + dot2bf(x.z, y.z) + dot2bf(x.w, y.w);
            s += __shfl_xor(s, 1);
            s += __shfl_xor(s, 2);   // all 4 lanes hold the full 32-dim sum
            if      (p == 0) r0 = s;
            else if (p == 1) r1 = s;
            else if (p == 2) r2 = s;
            else             r3 = s;
        }
        // lane j stores pass-j's result -> dense contiguous store
        const float v = (j == 0) ? r0 : (j == 1) ? r1 : (j == 2) ? r2 : r3;
        __builtin_nontemporal_store(v * 0.17677669529663687f,
                                    &out[base + (long long)c * 65536]);
    }
}

// ---------------------------------------------------------------------------
extern "C" void kernel_launch(void* const* d_in, const int* in_sizes, int n_in,
                              void* d_out, int out_size, void* d_ws, size_t ws_size,
                              hipStream_t stream)
{
    const float* feats = (const float*)d_in[0];
    const float* kw    = (const float*)d_in[1];
    const float* kb    = (const float*)d_in[2];
    const float* qw    = (const float*)d_in[3];
    const float* qb    = (const float*)d_in[4];
    const int*   idx   = (const int*)d_in[5];
    float*       out   = (float*)d_out;

    // Workspace: two bf16 tables [B*N, 32] = 8 MB each
    unsigned short* tkb = (unsigned short*)d_ws;
    unsigned short* tqb = tkb + (long long)NROWS * DOUT;

    proj_kernel<<<NROWS / 128, 512, 0, stream>>>(feats, kw, kb, qw, qb, tkb, tqb);
    gather_dot_kernel<<<2048, 256, 0, stream>>>(tkb, tqb, idx, out);
}